// Round 21
// baseline (224.095 us; speedup 1.0000x reference)
//
#include <hip/hip_runtime.h>
#include <hip/hip_bf16.h>

typedef __hip_bfloat16 bf16;
typedef __attribute__((ext_vector_type(8))) short short8v;
typedef __attribute__((ext_vector_type(4))) float f32x4;

constexpr int nB = 2;
constexpr int nS = 2048;
constexpr int nHID = 2048;
constexpr int nH = 16;
constexpr int nKV = 8;
constexpr int nD = 128;
constexpr int QS = 4096;  // fused qkv row stride (elems)
constexpr float kEps = 1e-6f;
constexpr float kScale = 0.08838834764831845f;  // 1/sqrt(128)

template <int N>
struct IC {
  static constexpr int value = N;
};

__device__ inline float b2f(unsigned short u) {
  return __uint_as_float(((unsigned)u) << 16);
}
__device__ inline float bf2f(bf16 v) { return __bfloat162float(v); }
__device__ inline short f2bs(float f) {
  bf16 h = __float2bfloat16(f);
  return *reinterpret_cast<short*>(&h);
}
__device__ inline unsigned pack2bf(float a, float b) {
  return ((unsigned)(unsigned short)f2bs(b) << 16) |
         (unsigned)(unsigned short)f2bs(a);
}

__device__ inline void gload_lds16(const bf16* g, bf16* l) {
  __builtin_amdgcn_global_load_lds(
      (const __attribute__((address_space(1))) void*)g,
      (__attribute__((address_space(3))) void*)l, 16, 0, 0);
}

template <int N>
__device__ inline void vwait() {
  asm volatile("s_waitcnt vmcnt(%0)" ::"n"(N) : "memory");
}

// ---------------------------------------------------------------------------
// Fused preprocessing (one launch, range-decoded):
//   blocks [0,12288):      weight transposes f32->bf16 (32x32 tiles)
//   blocks [12288,20480):   hs f32 -> bf16 convert (4 elems/thread)
//   blocks [20480,20992):   RoPE cos/sin table
// ---------------------------------------------------------------------------
__global__ __launch_bounds__(256) void preproc(
    const float* __restrict__ hs, const float* __restrict__ Wq,
    const float* __restrict__ Wk, const float* __restrict__ Wv,
    const float* __restrict__ Wo, bf16* __restrict__ hsb,
    bf16* __restrict__ Wcat, bf16* __restrict__ Wot,
    float2* __restrict__ tab) {
  int t = blockIdx.x;
  if (t < 12288) {  // ---- transposes
    const float* src;
    bf16* dst;
    int N;  // src is [2048][N]
    if (t < 4096) {
      src = Wq; dst = Wcat; N = 2048;
    } else if (t < 6144) {
      t -= 4096; src = Wk; dst = Wcat + (size_t)2048 * 2048; N = 1024;
    } else if (t < 8192) {
      t -= 6144; src = Wv; dst = Wcat + (size_t)3072 * 2048; N = 1024;
    } else {
      t -= 8192; src = Wo; dst = Wot; N = 2048;
    }
    const int tilesN = N >> 5;
    const int n0 = (t % tilesN) * 32, k0 = (t / tilesN) * 32;
    __shared__ float tb[32][33];
    const int c = threadIdx.x & 31, r8 = threadIdx.x >> 5;
#pragma unroll
    for (int i = 0; i < 4; ++i)
      tb[r8 + i * 8][c] = src[(size_t)(k0 + r8 + i * 8) * N + n0 + c];
    __syncthreads();
#pragma unroll
    for (int i = 0; i < 4; ++i)
      dst[(size_t)(n0 + r8 + i * 8) * 2048 + k0 + c] =
          __float2bfloat16(tb[c][r8 + i * 8]);
  } else if (t < 20480) {  // ---- hs convert
    const int i = ((t - 12288) * 256 + threadIdx.x) * 4;
    const float4 v = *reinterpret_cast<const float4*>(hs + i);
    ushort4 o;
    o.x = (unsigned short)f2bs(v.x);
    o.y = (unsigned short)f2bs(v.y);
    o.z = (unsigned short)f2bs(v.z);
    o.w = (unsigned short)f2bs(v.w);
    *reinterpret_cast<ushort4*>(hsb + i) = o;
  } else {  // ---- rope table
    const int idx = (t - 20480) * 256 + threadIdx.x;
    const int s = idx >> 6, j = idx & 63;
    const float invf = expf(-(float)j * (13.815510557964274f / 64.0f));
    const float ang = (float)s * invf;
    tab[idx] = make_float2(cosf(ang), sinf(ang));
  }
}

// ---------------------------------------------------------------------------
// Per-phase-interleaved MFMA GEMM (round-6 schedule + octet-swizzle pair),
// parameterized BM x BN. 512 thr = 8 waves (2m x 4n).
// KNORM=true (QKV instance): col-blocks 8..11 (K region, head-aligned) fuse
// RMSNorm+RoPE into the epilogue on the fp32 accumulator:
//   - row sum-sq: per-lane over NF frags, shfl_xor over lr, cross-wave
//     (wn^1) partial via 4KB LDS.
//   - rope partner c^64 = paired wave's same (m,n,r,lr) slot, exchanged via
//     a 72KB LDS buffer in two half-passes (reuses the staging LDS, post-loop,
//     barrier-separated). Block-uniform branch, epilogue-only.
// ---------------------------------------------------------------------------
template <int BM, int BN, bool KNORM, typename OUT_T>
__global__ __launch_bounds__(512) void gemm_8ph(
    const bf16* __restrict__ A, const bf16* __restrict__ Bt,
    OUT_T* __restrict__ C, int M, int N, int K,
    const float* __restrict__ kw, const float2* __restrict__ tab) {
  constexpr int LA = BM / 128;      // gloads per A k-half
  constexpr int LB = BN / 128;      // gloads per B k-half
  constexpr int MF = BM / 32;       // A frags per wave
  constexpr int MFH = MF / 2;       // A frags per phase
  constexpr int NF = BN / 64;       // B frags per wave
  constexpr int W = 2 * (LA + LB);  // steady-state vmcnt
  constexpr int LDSB = 2 * BM * 32 + 2 * BN * 32;  // elems per buffer
  __shared__ bf16 lds[2 * LDSB];

  const int tid = threadIdx.x;
  const int wave = tid >> 6, lane = tid & 63;
  const int lr = lane & 15, lg = lane >> 4;
  const int wm = wave >> 2, wn = wave & 3;
  const int m0 = blockIdx.y * BM, n0 = blockIdx.x * BN;
  const int srow = tid >> 2;
  const int scol = (((tid & 3) ^ ((tid >> 3) & 3)) << 3);
  const int fsw = (lr >> 1) & 3;

  auto stageA = [&](int t, int kk) {
    bf16* dst = lds + (t & 1) * LDSB + kk * (BM * 32) + wave * 512;
    const bf16* src = A + (size_t)(m0 + srow) * K + t * 64 + kk * 32 + scol;
#pragma unroll
    for (int j = 0; j < LA; ++j)
      gload_lds16(src + (size_t)(j * 128) * K, dst + j * 4096);
  };
  auto stageB = [&](int t, int kk) {
    bf16* dst =
        lds + (t & 1) * LDSB + 2 * BM * 32 + kk * (BN * 32) + wave * 512;
    const bf16* src = Bt + (size_t)(n0 + srow) * K + t * 64 + kk * 32 + scol;
#pragma unroll
    for (int j = 0; j < LB; ++j)
      gload_lds16(src + (size_t)(j * 128) * K, dst + j * 4096);
  };

  f32x4 acc[MF][NF];
#pragma unroll
  for (int m = 0; m < MF; ++m)
#pragma unroll
    for (int n = 0; n < NF; ++n) acc[m][n] = (f32x4){0.f, 0.f, 0.f, 0.f};
  short8v bfr[NF];

  auto phase = [&](auto WC, int buf, int kk, int mh, auto stageFn) {
    constexpr int WAIT = decltype(WC)::value;
    if constexpr (WAIT >= 0) vwait<WAIT>();
    __builtin_amdgcn_s_barrier();
    asm volatile("" ::: "memory");
    if (mh == 0) {
      const bf16* bb = lds + buf * LDSB + 2 * BM * 32 + kk * (BN * 32);
#pragma unroll
      for (int ni = 0; ni < NF; ++ni)
        bfr[ni] = *reinterpret_cast<const short8v*>(
            bb + (wn * (BN / 4) + ni * 16 + lr) * 32 + ((lg ^ fsw) << 3));
    }
    short8v af[MFH];
    const bf16* ab = lds + buf * LDSB + kk * (BM * 32);
#pragma unroll
    for (int ii = 0; ii < MFH; ++ii)
      af[ii] = *reinterpret_cast<const short8v*>(
          ab + (wm * (BM / 2) + (mh * MFH + ii) * 16 + lr) * 32 +
          ((lg ^ fsw) << 3));
    stageFn();
    asm volatile("s_waitcnt lgkmcnt(0)" ::: "memory");
    __builtin_amdgcn_sched_barrier(0);
    __builtin_amdgcn_s_setprio(1);
#pragma unroll
    for (int ii = 0; ii < MFH; ++ii)
#pragma unroll
      for (int ni = 0; ni < NF; ++ni)
        acc[mh * MFH + ii][ni] = __builtin_amdgcn_mfma_f32_16x16x32_bf16(
            af[ii], bfr[ni], acc[mh * MFH + ii][ni], 0, 0, 0);
    __builtin_amdgcn_s_setprio(0);
  };

  const int NT = K / 64;
  stageA(0, 0);
  stageB(0, 0);
  stageA(0, 1);
  stageB(0, 1);
  stageA(1, 0);
  stageB(1, 0);

  for (int t = 0; t < NT - 1; ++t) {
    const int buf = t & 1;
    phase(IC<W>{}, buf, 0, 0, [&] { stageA(t + 1, 1); });
    phase(IC<-1>{}, buf, 0, 1, [&] { stageB(t + 1, 1); });
    phase(IC<W>{}, buf, 1, 0, [&] {
      if (t < NT - 2) stageA(t + 2, 0);
    });
    phase(IC<-1>{}, buf, 1, 1, [&] {
      if (t < NT - 2) stageB(t + 2, 0);
    });
  }
  {  // peeled last tile
    const int buf = (NT - 1) & 1;
    phase(IC<LA + LB>{}, buf, 0, 0, [&] {});
    phase(IC<-1>{}, buf, 0, 1, [&] {});
    phase(IC<0>{}, buf, 1, 0, [&] {});
    phase(IC<-1>{}, buf, 1, 1, [&] {});
  }

  if constexpr (KNORM) {
    if (blockIdx.x >= 8 && blockIdx.x < 12) {  // K region, head-aligned
      // ---- 1) per-row sum of squares (this wave's 64-col slice)
      float ps[MF][4];
#pragma unroll
      for (int m = 0; m < MF; ++m)
#pragma unroll
        for (int r = 0; r < 4; ++r) {
          float s2 = 0.f;
#pragma unroll
          for (int n = 0; n < NF; ++n) s2 += acc[m][n][r] * acc[m][n][r];
#pragma unroll
          for (int off = 1; off < 16; off <<= 1) s2 += __shfl_xor(s2, off);
          ps[m][r] = s2;
        }
      float* sums = reinterpret_cast<float*>(lds);  // [4][256]
      __syncthreads();  // main-loop LDS reads fully done before overwrite
      if (lr == 0) {
#pragma unroll
        for (int m = 0; m < MF; ++m)
#pragma unroll
          for (int r = 0; r < 4; ++r)
            sums[wn * 256 + wm * 128 + m * 16 + 4 * lg + r] = ps[m][r];
      }
      __syncthreads();
      float inv[MF][4];
#pragma unroll
      for (int m = 0; m < MF; ++m)
#pragma unroll
        for (int r = 0; r < 4; ++r) {
          const int rp = wm * 128 + m * 16 + 4 * lg + r;
          const float tot = sums[wn * 256 + rp] + sums[(wn ^ 1) * 256 + rp];
          inv[m][r] = rsqrtf(tot * (1.0f / nD) + kEps);
        }
      __syncthreads();  // sums reads done before ex overwrites the region
      // ---- 2) rope via cross-wave exchange, two half-passes over n
      bf16* ex = lds;  // [8 waves][128 rows][36] bf16 (72KB)
      const int colbase = (wn & 1) * 64;  // head-local col base of this wave
      float kwl[NF];
#pragma unroll
      for (int n = 0; n < NF; ++n) kwl[n] = kw[colbase + n * 16 + lr];
      const int pw = wave ^ 1;  // partner wave (same wm, wn^1)
      for (int half = 0; half < 2; ++half) {
#pragma unroll
        for (int m = 0; m < MF; ++m)
#pragma unroll
          for (int nn = 0; nn < 2; ++nn) {
            const int n = 2 * half + nn;
#pragma unroll
            for (int r = 0; r < 4; ++r) {
              const float nv = acc[m][n][r] * inv[m][r] * kwl[n];
              ex[(wave * 128 + m * 16 + 4 * lg + r) * 36 + nn * 16 + lr] =
                  __float2bfloat16(nv);
            }
          }
        __syncthreads();
#pragma unroll
        for (int m = 0; m < MF; ++m)
#pragma unroll
          for (int nn = 0; nn < 2; ++nn) {
            const int n = 2 * half + nn;
#pragma unroll
            for (int r = 0; r < 4; ++r) {
              const int row = m0 + wm * 128 + m * 16 + 4 * lg + r;
              const int s = row & (nS - 1);
              const int c = colbase + n * 16 + lr;  // head-local col
              const float nv = acc[m][n][r] * inv[m][r] * kwl[n];
              const float partner = bf2f(
                  ex[(pw * 128 + m * 16 + 4 * lg + r) * 36 + nn * 16 + lr]);
              const float rot = (c < 64) ? -partner : partner;
              const float2 cs = tab[s * 64 + (c & 63)];
              const int col = n0 + wn * 64 + n * 16 + lr;
              C[(size_t)row * N + col] =
                  __float2bfloat16(nv * cs.x + rot * cs.y);
            }
          }
        __syncthreads();
      }
      return;
    }
  }

#pragma unroll
  for (int m = 0; m < MF; ++m)
#pragma unroll
    for (int n = 0; n < NF; ++n)
#pragma unroll
      for (int r = 0; r < 4; ++r) {
        const int row = m0 + wm * (BM / 2) + m * 16 + 4 * lg + r;
        const int col = n0 + wn * (BN / 4) + n * 16 + lr;
        if constexpr (sizeof(OUT_T) == 2)
          C[(size_t)row * N + col] = __float2bfloat16(acc[m][n][r]);
        else
          C[(size_t)row * N + col] = acc[m][n][r];
      }
}

// ---------------------------------------------------------------------------
// MFMA causal GQA flash attention, BQ=128 x 8 waves (512 threads).
// R16/R20-measured-best structure: fused Q RMSNorm/RoPE prologue;
// UNCONDITIONAL tile body (per-wave skip measured -25%: breaks T14 pipeline).
// ---------------------------------------------------------------------------
constexpr int BQ = 128, BKT = 64;

__global__ __launch_bounds__(512) void attn_mfma(
    const bf16* __restrict__ QKV, bf16* __restrict__ O,
    const float* __restrict__ qw, const float2* __restrict__ tab) {
  const int l = blockIdx.x;
  const int bh = l & 31;
  const int rr0 = l >> 5;
  const int qb = (rr0 < 8) ? 15 - rr0 : rr0 - 8;
  const int b = bh >> 4, h = bh & 15, kvh = h >> 1;
  const int q0 = qb * BQ;
  const int nt = 2 * qb + 2;
  const int tid = threadIdx.x;
  const int wave = tid >> 6, lane = tid & 63;
  const int lr = lane & 15, lg = lane >> 4;

  __shared__ bf16 Ks[BKT][136];   // row-major K tile (+8 pad)
  __shared__ bf16 Vt[nD][72];     // transposed V tile
  __shared__ bf16 Pl[8][16][72];  // per-wave P, layout [q][k]

  const bf16* Qbase = QKV + (size_t)b * nS * QS + h * nD;
  const bf16* Kbase = QKV + (size_t)b * nS * QS + 2048 + kvh * nD;
  const bf16* Vbase = QKV + (size_t)b * nS * QS + 3072 + kvh * nD;

  const int krow = tid >> 3, kcc = (tid & 7) * 16;   // K: 64 rows x 128
  const int vkey = tid & 63, vdc = (tid >> 6) * 16;  // V: 64 keys x 128 d

  short8v kreg[2], vreg[2];
  auto gload = [&](int kt) {
    const bf16* ksrc = Kbase + (size_t)(kt + krow) * QS + kcc;
    const bf16* vsrc = Vbase + (size_t)(kt + vkey) * QS + vdc;
    kreg[0] = *reinterpret_cast<const short8v*>(ksrc);
    kreg[1] = *reinterpret_cast<const short8v*>(ksrc + 8);
    vreg[0] = *reinterpret_cast<const short8v*>(vsrc);
    vreg[1] = *reinterpret_cast<const short8v*>(vsrc + 8);
  };
  auto lwrite = [&]() {
    *reinterpret_cast<short8v*>(&Ks[krow][kcc]) = kreg[0];
    *reinterpret_cast<short8v*>(&Ks[krow][kcc + 8]) = kreg[1];
#pragma unroll
    for (int i = 0; i < 2; ++i)
#pragma unroll
      for (int j = 0; j < 8; ++j)
        *reinterpret_cast<short*>(&Vt[vdc + 8 * i + j][vkey]) = vreg[i][j];
  };

  // ---- Q load with fused RMSNorm + RoPE
  short8v qf[4];
  {
    const int qrow_i = q0 + 16 * wave + lr;
    const bf16* qrow = Qbase + (size_t)qrow_i * QS;
    float x[4][8];
    float ss = 0.f;
#pragma unroll
    for (int dc = 0; dc < 4; ++dc) {
      const short8v raw =
          *reinterpret_cast<const short8v*>(qrow + 32 * dc + 8 * lg);
#pragma unroll
      for (int j2 = 0; j2 < 8; ++j2) {
        const float v = b2f((unsigned short)raw[j2]);
        x[dc][j2] = v;
        ss += v * v;
      }
    }
    ss += __shfl_xor(ss, 16);
    ss += __shfl_xor(ss, 32);
    const float inv = rsqrtf(ss * (1.0f / nD) + kEps);
#pragma unroll
    for (int dc = 0; dc < 4; ++dc) {
      const float4 w0 = *reinterpret_cast<const float4*>(qw + 32 * dc + 8 * lg);
      const float4 w1 =
          *reinterpret_cast<const float4*>(qw + 32 * dc + 8 * lg + 4);
      const float wv[8] = {w0.x, w0.y, w0.z, w0.w, w1.x, w1.y, w1.z, w1.w};
#pragma unroll
      for (int j2 = 0; j2 < 8; ++j2) x[dc][j2] *= inv * wv[j2];
    }
#pragma unroll
    for (int dc = 0; dc < 4; ++dc) {
      short8v q8;
#pragma unroll
      for (int j2 = 0; j2 < 8; ++j2) {
        const int c = 32 * dc + 8 * lg + j2;
        const float2 cs = tab[qrow_i * 64 + (c & 63)];
        const float rot = (dc < 2) ? -x[dc ^ 2][j2] : x[dc ^ 2][j2];
        q8[j2] = f2bs(x[dc][j2] * cs.x + rot * cs.y);
      }
      qf[dc] = q8;
    }
  }

  f32x4 of[8];
#pragma unroll
  for (int n = 0; n < 8; ++n) of[n] = (f32x4){0.f, 0.f, 0.f, 0.f};
  float m_run = -1e30f, l_run = 0.f;

  gload(0);
  lwrite();
  __syncthreads();

  for (int j = 0; j < nt; ++j) {
    const int kt = j * BKT;
    const bool have_next = (j + 1 < nt);
    if (have_next) gload((j + 1) * BKT);  // T14: issue early, write later

    // ---- QK^T swapped: S^T[k=16sub+4lg+r][q=lr]
    f32x4 s[4];
    __builtin_amdgcn_s_setprio(1);
#pragma unroll
    for (int sub = 0; sub < 4; ++sub) {
      f32x4 acc = {0.f, 0.f, 0.f, 0.f};
#pragma unroll
      for (int dc = 0; dc < 4; ++dc) {
        const short8v kf = *reinterpret_cast<const short8v*>(
            &Ks[16 * sub + lr][32 * dc + 8 * lg]);
        acc = __builtin_amdgcn_mfma_f32_16x16x32_bf16(kf, qf[dc], acc, 0, 0, 0);
      }
      s[sub] = acc;
    }
    __builtin_amdgcn_s_setprio(0);

    // ---- scale + causal mask (wave-dependent: BQ spans 2 diag tiles)
    const bool needMask = (kt + BKT > q0 + 16 * wave);
#pragma unroll
    for (int sub = 0; sub < 4; ++sub)
#pragma unroll
      for (int r = 0; r < 4; ++r) {
        float v = s[sub][r] * kScale;
        if (needMask && (kt + 16 * sub + 4 * lg + r > q0 + 16 * wave + lr))
          v = -1e30f;
        s[sub][r] = v;
      }

    // ---- online softmax, column q = lr (lanes lr, lr+16, +32, +48)
    float pmax = -1e30f;
#pragma unroll
    for (int sub = 0; sub < 4; ++sub)
#pragma unroll
      for (int r = 0; r < 4; ++r) pmax = fmaxf(pmax, s[sub][r]);
    pmax = fmaxf(pmax, __shfl_xor(pmax, 16));
    pmax = fmaxf(pmax, __shfl_xor(pmax, 32));

    if (!__all(pmax - m_run <= 8.f)) {  // T13 defer-rescale
      const float mt = fmaxf(m_run, pmax);
      const float corr = __expf(m_run - mt);
#pragma unroll
      for (int n = 0; n < 8; ++n) of[n] *= corr;
      l_run *= corr;
      m_run = mt;
    }

    float p[4][4];
    float lsum = 0.f;
#pragma unroll
    for (int sub = 0; sub < 4; ++sub)
#pragma unroll
      for (int r = 0; r < 4; ++r) {
        const float e = __expf(s[sub][r] - m_run);
        p[sub][r] = e;
        lsum += e;
      }
    lsum += __shfl_xor(lsum, 16);
    lsum += __shfl_xor(lsum, 32);
    l_run += lsum;

    // ---- P -> Pl[q][k]: 8 packed b32 writes (wave-private)
#pragma unroll
    for (int sub = 0; sub < 4; ++sub)
#pragma unroll
      for (int rp = 0; rp < 2; ++rp)
        *reinterpret_cast<unsigned*>(
            &Pl[wave][lr][16 * sub + 4 * lg + 2 * rp]) =
            pack2bf(p[sub][2 * rp], p[sub][2 * rp + 1]);

    // ---- PV as O^T: of[n] = O^T[d=16n+4lg+r][q=lr]
    __builtin_amdgcn_s_setprio(1);
#pragma unroll
    for (int kk = 0; kk < 2; ++kk) {
      const short8v pb =
          *reinterpret_cast<const short8v*>(&Pl[wave][lr][32 * kk + 8 * lg]);
#pragma unroll
      for (int n = 0; n < 8; ++n) {
        const short8v vf = *reinterpret_cast<const short8v*>(
            &Vt[16 * n + lr][32 * kk + 8 * lg]);
        of[n] = __builtin_amdgcn_mfma_f32_16x16x32_bf16(vf, pb, of[n], 0, 0, 0);
      }
    }
    __builtin_amdgcn_s_setprio(0);

    if (have_next) {
      __syncthreads();  // all waves done reading Ks/Vt of tile j
      lwrite();
      __syncthreads();  // next tile visible
    }
  }

  // ---- epilogue
  {
    const float inv = 1.0f / l_run;
    bf16* orow = O + ((size_t)(b * nS + q0 + 16 * wave + lr)) * (nH * nD) +
                 h * nD + 4 * lg;
#pragma unroll
    for (int n = 0; n < 8; ++n)
#pragma unroll
      for (int rp = 0; rp < 2; ++rp)
        *reinterpret_cast<unsigned*>(orow + 16 * n + 2 * rp) =
            pack2bf(of[n][2 * rp] * inv, of[n][2 * rp + 1] * inv);
  }
}

// ---------------------------------------------------------------------------
extern "C" void kernel_launch(void* const* d_in, const int* in_sizes, int n_in,
                              void* d_out, int out_size, void* d_ws,
                              size_t ws_size, hipStream_t stream) {
  const float* hs = (const float*)d_in[0];
  const float* Wq = (const float*)d_in[1];
  const float* Wk = (const float*)d_in[2];
  const float* Wv = (const float*)d_in[3];
  const float* Wo = (const float*)d_in[4];
  const float* qw = (const float*)d_in[5];
  const float* kw = (const float*)d_in[6];

  const int M = nB * nS;  // 4096
  char* ws = (char*)d_ws;
  size_t off = 0;
  auto alloc = [&](size_t bytes) {
    char* p = ws + off;
    off += bytes;
    return p;
  };
  bf16* hsb = (bf16*)alloc((size_t)M * nHID * 2);    // 16.8 MB
  bf16* att = hsb;                                   // reused after QKV GEMM
  bf16* qkv = (bf16*)alloc((size_t)M * QS * 2);      // 33.6 MB
  bf16* Wcat = (bf16*)alloc((size_t)QS * nHID * 2);  // 16.8 MB
  bf16* Wot = (bf16*)alloc((size_t)nH * nD * nHID * 2);
  float2* tab = (float2*)alloc((size_t)nS * 64 * 8);  // 1 MB RoPE table
  float* out = (float*)d_out;

  // fused preprocessing: transposes + hs convert + rope table (one launch)
  preproc<<<dim3(20992), 256, 0, stream>>>(hs, Wq, Wk, Wv, Wo, hsb, Wcat, Wot,
                                           tab);

  // fused QKV projection with K-norm/rope fused into the epilogue
  gemm_8ph<256, 256, true, bf16><<<dim3(QS / 256, M / 256), 512, 0, stream>>>(
      hsb, Wcat, qkv, M, QS, nHID, kw, tab);

  attn_mfma<<<dim3(512), 512, 0, stream>>>(qkv, att, qw, tab);

  // output projection: [4096 x 2048] @ [2048 x 2048] -> out (fp32)
  gemm_8ph<128, 256, false, float>
      <<<dim3(nHID / 256, M / 128), 512, 0, stream>>>(att, Wot, out, M, nHID,
                                                      nH * nD, nullptr,
                                                      nullptr);
}

// Round 22
// 217.767 us; speedup vs baseline: 1.0291x; 1.0291x over previous
//
#include <hip/hip_runtime.h>
#include <hip/hip_bf16.h>

typedef __hip_bfloat16 bf16;
typedef __attribute__((ext_vector_type(8))) short short8v;
typedef __attribute__((ext_vector_type(4))) float f32x4;

constexpr int nB = 2;
constexpr int nS = 2048;
constexpr int nHID = 2048;
constexpr int nH = 16;
constexpr int nKV = 8;
constexpr int nD = 128;
constexpr int QS = 4096;  // fused qkv row stride (elems)
constexpr float kEps = 1e-6f;
constexpr float kScale = 0.08838834764831845f;  // 1/sqrt(128)

template <int N>
struct IC {
  static constexpr int value = N;
};

__device__ inline float b2f(unsigned short u) {
  return __uint_as_float(((unsigned)u) << 16);
}
__device__ inline float bf2f(bf16 v) { return __bfloat162float(v); }
__device__ inline short f2bs(float f) {
  bf16 h = __float2bfloat16(f);
  return *reinterpret_cast<short*>(&h);
}
__device__ inline unsigned pack2bf(float a, float b) {
  return ((unsigned)(unsigned short)f2bs(b) << 16) |
         (unsigned)(unsigned short)f2bs(a);
}

__device__ inline void gload_lds16(const bf16* g, bf16* l) {
  __builtin_amdgcn_global_load_lds(
      (const __attribute__((address_space(1))) void*)g,
      (__attribute__((address_space(3))) void*)l, 16, 0, 0);
}

template <int N>
__device__ inline void vwait() {
  asm volatile("s_waitcnt vmcnt(%0)" ::"n"(N) : "memory");
}

// ---------------------------------------------------------------------------
// Fused preprocessing (one launch, range-decoded):
//   blocks [0,12288):      weight transposes f32->bf16 (32x32 tiles)
//   blocks [12288,20480):   hs f32 -> bf16 convert (4 elems/thread)
//   blocks [20480,20992):   RoPE cos/sin table
// ---------------------------------------------------------------------------
__global__ __launch_bounds__(256) void preproc(
    const float* __restrict__ hs, const float* __restrict__ Wq,
    const float* __restrict__ Wk, const float* __restrict__ Wv,
    const float* __restrict__ Wo, bf16* __restrict__ hsb,
    bf16* __restrict__ Wcat, bf16* __restrict__ Wot,
    float2* __restrict__ tab) {
  int t = blockIdx.x;
  if (t < 12288) {  // ---- transposes
    const float* src;
    bf16* dst;
    int N;  // src is [2048][N]
    if (t < 4096) {
      src = Wq; dst = Wcat; N = 2048;
    } else if (t < 6144) {
      t -= 4096; src = Wk; dst = Wcat + (size_t)2048 * 2048; N = 1024;
    } else if (t < 8192) {
      t -= 6144; src = Wv; dst = Wcat + (size_t)3072 * 2048; N = 1024;
    } else {
      t -= 8192; src = Wo; dst = Wot; N = 2048;
    }
    const int tilesN = N >> 5;
    const int n0 = (t % tilesN) * 32, k0 = (t / tilesN) * 32;
    __shared__ float tb[32][33];
    const int c = threadIdx.x & 31, r8 = threadIdx.x >> 5;
#pragma unroll
    for (int i = 0; i < 4; ++i)
      tb[r8 + i * 8][c] = src[(size_t)(k0 + r8 + i * 8) * N + n0 + c];
    __syncthreads();
#pragma unroll
    for (int i = 0; i < 4; ++i)
      dst[(size_t)(n0 + r8 + i * 8) * 2048 + k0 + c] =
          __float2bfloat16(tb[c][r8 + i * 8]);
  } else if (t < 20480) {  // ---- hs convert
    const int i = ((t - 12288) * 256 + threadIdx.x) * 4;
    const float4 v = *reinterpret_cast<const float4*>(hs + i);
    ushort4 o;
    o.x = (unsigned short)f2bs(v.x);
    o.y = (unsigned short)f2bs(v.y);
    o.z = (unsigned short)f2bs(v.z);
    o.w = (unsigned short)f2bs(v.w);
    *reinterpret_cast<ushort4*>(hsb + i) = o;
  } else {  // ---- rope table
    const int idx = (t - 20480) * 256 + threadIdx.x;
    const int s = idx >> 6, j = idx & 63;
    const float invf = expf(-(float)j * (13.815510557964274f / 64.0f));
    const float ang = (float)s * invf;
    tab[idx] = make_float2(cosf(ang), sinf(ang));
  }
}

// ---------------------------------------------------------------------------
// Per-phase-interleaved MFMA GEMM (round-6 schedule + octet-swizzle pair).
// BN fixed at 256; BM in {256,128}. Measured-best configuration (217.8 us).
// No epilogue fusion: KNORM (R21) cost +4 us via main-loop register pressure.
// ---------------------------------------------------------------------------
template <int BM, typename OUT_T>
__global__ __launch_bounds__(512) void gemm_8ph(
    const bf16* __restrict__ A, const bf16* __restrict__ Bt,
    OUT_T* __restrict__ C, int M, int N, int K) {
  constexpr int LA = BM / 128;      // gloads per A k-half
  constexpr int LB = 2;             // gloads per B k-half
  constexpr int MF = BM / 32;       // A frags per wave
  constexpr int MFH = MF / 2;       // A frags per phase
  constexpr int W = 2 * (LA + LB);  // steady-state vmcnt
  constexpr int LDSB = 2 * BM * 32 + 2 * 256 * 32;  // elems per buffer
  __shared__ bf16 lds[2 * LDSB];

  const int tid = threadIdx.x;
  const int wave = tid >> 6, lane = tid & 63;
  const int lr = lane & 15, lg = lane >> 4;
  const int wm = wave >> 2, wn = wave & 3;
  const int m0 = blockIdx.y * BM, n0 = blockIdx.x * 256;
  const int srow = tid >> 2;
  const int scol = (((tid & 3) ^ ((tid >> 3) & 3)) << 3);
  const int fsw = (lr >> 1) & 3;

  auto stageA = [&](int t, int kk) {
    bf16* dst = lds + (t & 1) * LDSB + kk * (BM * 32) + wave * 512;
    const bf16* src = A + (size_t)(m0 + srow) * K + t * 64 + kk * 32 + scol;
#pragma unroll
    for (int j = 0; j < LA; ++j)
      gload_lds16(src + (size_t)(j * 128) * K, dst + j * 4096);
  };
  auto stageB = [&](int t, int kk) {
    bf16* dst =
        lds + (t & 1) * LDSB + 2 * BM * 32 + kk * (256 * 32) + wave * 512;
    const bf16* src = Bt + (size_t)(n0 + srow) * K + t * 64 + kk * 32 + scol;
#pragma unroll
    for (int j = 0; j < LB; ++j)
      gload_lds16(src + (size_t)(j * 128) * K, dst + j * 4096);
  };

  f32x4 acc[MF][4];
#pragma unroll
  for (int m = 0; m < MF; ++m)
#pragma unroll
    for (int n = 0; n < 4; ++n) acc[m][n] = (f32x4){0.f, 0.f, 0.f, 0.f};
  short8v bfr[4];

  auto phase = [&](auto WC, int buf, int kk, int mh, auto stageFn) {
    constexpr int WAIT = decltype(WC)::value;
    if constexpr (WAIT >= 0) vwait<WAIT>();
    __builtin_amdgcn_s_barrier();
    asm volatile("" ::: "memory");
    if (mh == 0) {
      const bf16* bb = lds + buf * LDSB + 2 * BM * 32 + kk * (256 * 32);
#pragma unroll
      for (int ni = 0; ni < 4; ++ni)
        bfr[ni] = *reinterpret_cast<const short8v*>(
            bb + (wn * 64 + ni * 16 + lr) * 32 + ((lg ^ fsw) << 3));
    }
    short8v af[MFH];
    const bf16* ab = lds + buf * LDSB + kk * (BM * 32);
#pragma unroll
    for (int ii = 0; ii < MFH; ++ii)
      af[ii] = *reinterpret_cast<const short8v*>(
          ab + (wm * (BM / 2) + (mh * MFH + ii) * 16 + lr) * 32 +
          ((lg ^ fsw) << 3));
    stageFn();
    asm volatile("s_waitcnt lgkmcnt(0)" ::: "memory");
    __builtin_amdgcn_sched_barrier(0);
    __builtin_amdgcn_s_setprio(1);
#pragma unroll
    for (int ii = 0; ii < MFH; ++ii)
#pragma unroll
      for (int ni = 0; ni < 4; ++ni)
        acc[mh * MFH + ii][ni] = __builtin_amdgcn_mfma_f32_16x16x32_bf16(
            af[ii], bfr[ni], acc[mh * MFH + ii][ni], 0, 0, 0);
    __builtin_amdgcn_s_setprio(0);
  };

  const int NT = K / 64;
  stageA(0, 0);
  stageB(0, 0);
  stageA(0, 1);
  stageB(0, 1);
  stageA(1, 0);
  stageB(1, 0);

  for (int t = 0; t < NT - 1; ++t) {
    const int buf = t & 1;
    phase(IC<W>{}, buf, 0, 0, [&] { stageA(t + 1, 1); });
    phase(IC<-1>{}, buf, 0, 1, [&] { stageB(t + 1, 1); });
    phase(IC<W>{}, buf, 1, 0, [&] {
      if (t < NT - 2) stageA(t + 2, 0);
    });
    phase(IC<-1>{}, buf, 1, 1, [&] {
      if (t < NT - 2) stageB(t + 2, 0);
    });
  }
  {  // peeled last tile
    const int buf = (NT - 1) & 1;
    phase(IC<LA + LB>{}, buf, 0, 0, [&] {});
    phase(IC<-1>{}, buf, 0, 1, [&] {});
    phase(IC<0>{}, buf, 1, 0, [&] {});
    phase(IC<-1>{}, buf, 1, 1, [&] {});
  }

#pragma unroll
  for (int m = 0; m < MF; ++m)
#pragma unroll
    for (int n = 0; n < 4; ++n)
#pragma unroll
      for (int r = 0; r < 4; ++r) {
        const int row = m0 + wm * (BM / 2) + m * 16 + 4 * lg + r;
        const int col = n0 + wn * 64 + n * 16 + lr;
        if constexpr (sizeof(OUT_T) == 2)
          C[(size_t)row * N + col] = __float2bfloat16(acc[m][n][r]);
        else
          C[(size_t)row * N + col] = acc[m][n][r];
      }
}

// ---------------------------------------------------------------------------
// K-only RMSNorm + RoPE on the fused qkv buffer (Q is fused into attn).
// ---------------------------------------------------------------------------
__global__ __launch_bounds__(128) void norm_rope_k(
    bf16* __restrict__ qkv, const float* __restrict__ kw,
    const float2* __restrict__ tab) {
  const int row = blockIdx.x;
  const int head = blockIdx.y;
  const int t = threadIdx.x;
  const int s = row & (nS - 1);
  bf16* xp = qkv + (size_t)row * QS + 2048 + head * nD;
  const float v = bf2f(xp[t]);
  float ss = v * v;
#pragma unroll
  for (int off = 32; off > 0; off >>= 1) ss += __shfl_xor(ss, off);
  __shared__ float wsum[2];
  __shared__ float buf[nD];
  if ((t & 63) == 0) wsum[t >> 6] = ss;
  __syncthreads();
  const float inv = rsqrtf((wsum[0] + wsum[1]) * (1.0f / nD) + kEps);
  const float nv = v * inv * kw[t];
  buf[t] = nv;
  __syncthreads();
  const float partner = buf[t ^ 64];
  const float rot = (t < 64) ? -partner : partner;
  const int j = t & 63;
  const float2 cs = tab[s * 64 + j];
  const float outv = nv * cs.x + rot * cs.y;
  xp[t] = __float2bfloat16(outv);
}

// ---------------------------------------------------------------------------
// MFMA causal GQA flash attention, BQ=128 x 8 waves (512 threads).
// Measured-best structure: fused Q RMSNorm/RoPE prologue; UNCONDITIONAL
// tile body (per-wave skip measured -25%: breaks the T14 prefetch pipeline;
// KNORM-style epilogue fusion measured +4us via register pressure).
// ---------------------------------------------------------------------------
constexpr int BQ = 128, BKT = 64;

__global__ __launch_bounds__(512) void attn_mfma(
    const bf16* __restrict__ QKV, bf16* __restrict__ O,
    const float* __restrict__ qw, const float2* __restrict__ tab) {
  const int l = blockIdx.x;
  const int bh = l & 31;
  const int rr0 = l >> 5;
  const int qb = (rr0 < 8) ? 15 - rr0 : rr0 - 8;
  const int b = bh >> 4, h = bh & 15, kvh = h >> 1;
  const int q0 = qb * BQ;
  const int nt = 2 * qb + 2;
  const int tid = threadIdx.x;
  const int wave = tid >> 6, lane = tid & 63;
  const int lr = lane & 15, lg = lane >> 4;

  __shared__ bf16 Ks[BKT][136];   // row-major K tile (+8 pad)
  __shared__ bf16 Vt[nD][72];     // transposed V tile
  __shared__ bf16 Pl[8][16][72];  // per-wave P, layout [q][k]

  const bf16* Qbase = QKV + (size_t)b * nS * QS + h * nD;
  const bf16* Kbase = QKV + (size_t)b * nS * QS + 2048 + kvh * nD;
  const bf16* Vbase = QKV + (size_t)b * nS * QS + 3072 + kvh * nD;

  const int krow = tid >> 3, kcc = (tid & 7) * 16;   // K: 64 rows x 128
  const int vkey = tid & 63, vdc = (tid >> 6) * 16;  // V: 64 keys x 128 d

  short8v kreg[2], vreg[2];
  auto gload = [&](int kt) {
    const bf16* ksrc = Kbase + (size_t)(kt + krow) * QS + kcc;
    const bf16* vsrc = Vbase + (size_t)(kt + vkey) * QS + vdc;
    kreg[0] = *reinterpret_cast<const short8v*>(ksrc);
    kreg[1] = *reinterpret_cast<const short8v*>(ksrc + 8);
    vreg[0] = *reinterpret_cast<const short8v*>(vsrc);
    vreg[1] = *reinterpret_cast<const short8v*>(vsrc + 8);
  };
  auto lwrite = [&]() {
    *reinterpret_cast<short8v*>(&Ks[krow][kcc]) = kreg[0];
    *reinterpret_cast<short8v*>(&Ks[krow][kcc + 8]) = kreg[1];
#pragma unroll
    for (int i = 0; i < 2; ++i)
#pragma unroll
      for (int j = 0; j < 8; ++j)
        *reinterpret_cast<short*>(&Vt[vdc + 8 * i + j][vkey]) = vreg[i][j];
  };

  // ---- Q load with fused RMSNorm + RoPE
  short8v qf[4];
  {
    const int qrow_i = q0 + 16 * wave + lr;
    const bf16* qrow = Qbase + (size_t)qrow_i * QS;
    float x[4][8];
    float ss = 0.f;
#pragma unroll
    for (int dc = 0; dc < 4; ++dc) {
      const short8v raw =
          *reinterpret_cast<const short8v*>(qrow + 32 * dc + 8 * lg);
#pragma unroll
      for (int j2 = 0; j2 < 8; ++j2) {
        const float v = b2f((unsigned short)raw[j2]);
        x[dc][j2] = v;
        ss += v * v;
      }
    }
    ss += __shfl_xor(ss, 16);
    ss += __shfl_xor(ss, 32);
    const float inv = rsqrtf(ss * (1.0f / nD) + kEps);
#pragma unroll
    for (int dc = 0; dc < 4; ++dc) {
      const float4 w0 = *reinterpret_cast<const float4*>(qw + 32 * dc + 8 * lg);
      const float4 w1 =
          *reinterpret_cast<const float4*>(qw + 32 * dc + 8 * lg + 4);
      const float wv[8] = {w0.x, w0.y, w0.z, w0.w, w1.x, w1.y, w1.z, w1.w};
#pragma unroll
      for (int j2 = 0; j2 < 8; ++j2) x[dc][j2] *= inv * wv[j2];
    }
#pragma unroll
    for (int dc = 0; dc < 4; ++dc) {
      short8v q8;
#pragma unroll
      for (int j2 = 0; j2 < 8; ++j2) {
        const int c = 32 * dc + 8 * lg + j2;
        const float2 cs = tab[qrow_i * 64 + (c & 63)];
        const float rot = (dc < 2) ? -x[dc ^ 2][j2] : x[dc ^ 2][j2];
        q8[j2] = f2bs(x[dc][j2] * cs.x + rot * cs.y);
      }
      qf[dc] = q8;
    }
  }

  f32x4 of[8];
#pragma unroll
  for (int n = 0; n < 8; ++n) of[n] = (f32x4){0.f, 0.f, 0.f, 0.f};
  float m_run = -1e30f, l_run = 0.f;

  gload(0);
  lwrite();
  __syncthreads();

  for (int j = 0; j < nt; ++j) {
    const int kt = j * BKT;
    const bool have_next = (j + 1 < nt);
    if (have_next) gload((j + 1) * BKT);  // T14: issue early, write later

    // ---- QK^T swapped: S^T[k=16sub+4lg+r][q=lr]
    f32x4 s[4];
    __builtin_amdgcn_s_setprio(1);
#pragma unroll
    for (int sub = 0; sub < 4; ++sub) {
      f32x4 acc = {0.f, 0.f, 0.f, 0.f};
#pragma unroll
      for (int dc = 0; dc < 4; ++dc) {
        const short8v kf = *reinterpret_cast<const short8v*>(
            &Ks[16 * sub + lr][32 * dc + 8 * lg]);
        acc = __builtin_amdgcn_mfma_f32_16x16x32_bf16(kf, qf[dc], acc, 0, 0, 0);
      }
      s[sub] = acc;
    }
    __builtin_amdgcn_s_setprio(0);

    // ---- scale + causal mask (wave-dependent: BQ spans 2 diag tiles)
    const bool needMask = (kt + BKT > q0 + 16 * wave);
#pragma unroll
    for (int sub = 0; sub < 4; ++sub)
#pragma unroll
      for (int r = 0; r < 4; ++r) {
        float v = s[sub][r] * kScale;
        if (needMask && (kt + 16 * sub + 4 * lg + r > q0 + 16 * wave + lr))
          v = -1e30f;
        s[sub][r] = v;
      }

    // ---- online softmax, column q = lr (lanes lr, lr+16, +32, +48)
    float pmax = -1e30f;
#pragma unroll
    for (int sub = 0; sub < 4; ++sub)
#pragma unroll
      for (int r = 0; r < 4; ++r) pmax = fmaxf(pmax, s[sub][r]);
    pmax = fmaxf(pmax, __shfl_xor(pmax, 16));
    pmax = fmaxf(pmax, __shfl_xor(pmax, 32));

    if (!__all(pmax - m_run <= 8.f)) {  // T13 defer-rescale
      const float mt = fmaxf(m_run, pmax);
      const float corr = __expf(m_run - mt);
#pragma unroll
      for (int n = 0; n < 8; ++n) of[n] *= corr;
      l_run *= corr;
      m_run = mt;
    }

    float p[4][4];
    float lsum = 0.f;
#pragma unroll
    for (int sub = 0; sub < 4; ++sub)
#pragma unroll
      for (int r = 0; r < 4; ++r) {
        const float e = __expf(s[sub][r] - m_run);
        p[sub][r] = e;
        lsum += e;
      }
    lsum += __shfl_xor(lsum, 16);
    lsum += __shfl_xor(lsum, 32);
    l_run += lsum;

    // ---- P -> Pl[q][k]: 8 packed b32 writes (wave-private)
#pragma unroll
    for (int sub = 0; sub < 4; ++sub)
#pragma unroll
      for (int rp = 0; rp < 2; ++rp)
        *reinterpret_cast<unsigned*>(
            &Pl[wave][lr][16 * sub + 4 * lg + 2 * rp]) =
            pack2bf(p[sub][2 * rp], p[sub][2 * rp + 1]);

    // ---- PV as O^T: of[n] = O^T[d=16n+4lg+r][q=lr]
    __builtin_amdgcn_s_setprio(1);
#pragma unroll
    for (int kk = 0; kk < 2; ++kk) {
      const short8v pb =
          *reinterpret_cast<const short8v*>(&Pl[wave][lr][32 * kk + 8 * lg]);
#pragma unroll
      for (int n = 0; n < 8; ++n) {
        const short8v vf = *reinterpret_cast<const short8v*>(
            &Vt[16 * n + lr][32 * kk + 8 * lg]);
        of[n] = __builtin_amdgcn_mfma_f32_16x16x32_bf16(vf, pb, of[n], 0, 0, 0);
      }
    }
    __builtin_amdgcn_s_setprio(0);

    if (have_next) {
      __syncthreads();  // all waves done reading Ks/Vt of tile j
      lwrite();
      __syncthreads();  // next tile visible
    }
  }

  // ---- epilogue
  {
    const float inv = 1.0f / l_run;
    bf16* orow = O + ((size_t)(b * nS + q0 + 16 * wave + lr)) * (nH * nD) +
                 h * nD + 4 * lg;
#pragma unroll
    for (int n = 0; n < 8; ++n)
#pragma unroll
      for (int rp = 0; rp < 2; ++rp)
        *reinterpret_cast<unsigned*>(orow + 16 * n + 2 * rp) =
            pack2bf(of[n][2 * rp] * inv, of[n][2 * rp + 1] * inv);
  }
}

// ---------------------------------------------------------------------------
extern "C" void kernel_launch(void* const* d_in, const int* in_sizes, int n_in,
                              void* d_out, int out_size, void* d_ws,
                              size_t ws_size, hipStream_t stream) {
  const float* hs = (const float*)d_in[0];
  const float* Wq = (const float*)d_in[1];
  const float* Wk = (const float*)d_in[2];
  const float* Wv = (const float*)d_in[3];
  const float* Wo = (const float*)d_in[4];
  const float* qw = (const float*)d_in[5];
  const float* kw = (const float*)d_in[6];

  const int M = nB * nS;  // 4096
  char* ws = (char*)d_ws;
  size_t off = 0;
  auto alloc = [&](size_t bytes) {
    char* p = ws + off;
    off += bytes;
    return p;
  };
  bf16* hsb = (bf16*)alloc((size_t)M * nHID * 2);    // 16.8 MB
  bf16* att = hsb;                                   // reused after QKV GEMM
  bf16* qkv = (bf16*)alloc((size_t)M * QS * 2);      // 33.6 MB
  bf16* Wcat = (bf16*)alloc((size_t)QS * nHID * 2);  // 16.8 MB
  bf16* Wot = (bf16*)alloc((size_t)nH * nD * nHID * 2);
  float2* tab = (float2*)alloc((size_t)nS * 64 * 8);  // 1 MB RoPE table
  float* out = (float*)d_out;

  // fused preprocessing: transposes + hs convert + rope table (one launch)
  preproc<<<dim3(20992), 256, 0, stream>>>(hs, Wq, Wk, Wv, Wo, hsb, Wcat, Wot,
                                           tab);

  // fused QKV projection: [4096 x 2048] @ [2048 x 4096]^T-layout -> qkv
  gemm_8ph<256, bf16><<<dim3(QS / 256, M / 256), 512, 0, stream>>>(
      hsb, Wcat, qkv, M, QS, nHID);

  // K-only norm+rope (Q's is fused into attn)
  norm_rope_k<<<dim3(M, nKV), 128, 0, stream>>>(qkv, kw, tab);

  attn_mfma<<<dim3(512), 512, 0, stream>>>(qkv, att, qw, tab);

  // output projection: [4096 x 2048] @ [2048 x 2048] -> out (fp32)
  gemm_8ph<128, float><<<dim3(nHID / 256, M / 128), 512, 0, stream>>>(
      att, Wot, out, M, nHID, nH * nD);
}